// Round 5
// baseline (609.335 us; speedup 1.0000x reference)
//
#include <hip/hip_runtime.h>
#include <math.h>

// Problem constants (from reference: z (32,4096,256) f32, embed (1024,256) f32)
#define N_TOK   131072
#define DIM     256
#define K_CODE  1024
#define MARGIN1 3e-2f     // stage-1 (K=256 bf16) top1-top2 gap below which token is redone
                          // at K=768: dropped-term error sigma ~1.6e-3/code -> >=10 sigma
#define MARGIN2 2e-3f     // K=768 gap below which we redo in fp64 (proven in prior rounds)

// Workspace layout (bytes)
#define WS_COUNTS   0         // 1024 * int      (histogram)
#define WS_LOSSFIX  4096      // double          (recheck loss correction)
#define WS_RCOUNT2  4104      // int             (fp64 recheck-list count)
#define WS_RCOUNT1  4108      // int             (stage-1 redo-list count)
#define WS_PART     8192      // 1280 * double   (loss partials: 1024 stage1 + 256 redo)
#define WS_FIDX     20480     // N_TOK * int     (argmax index per token)
#define WS_RLIST2   1048576   // N_TOK * int     (tokens needing fp64 recheck)
#define WS_RLIST1   1572864   // N_TOK/... int   (tokens needing K=768 redo; cap 128K ints)
#define WS_BEXT     2097152   // 1024*768 bf16 = 1.5 MB packed normalized codebook

#define CHUNK_BYTES 49152     // 32 codes x 768 x 2B: one full-K chunk image in bext

// Output layout (floats): z_q_st[33554432], loss, perplexity, indices[131072]
#define OUT_LOSS  33554432
#define OUT_PERP  33554433
#define OUT_IDX   33554434

typedef __bf16 bf16x8 __attribute__((ext_vector_type(8)));
typedef float  f32x4  __attribute__((ext_vector_type(4)));

// round-to-nearest-even fp32 -> bf16 bits
static __device__ __forceinline__ unsigned short f2bf(float f) {
    unsigned int u = __float_as_uint(f);
    u += 0x7FFFu + ((u >> 16) & 1u);
    return (unsigned short)(u >> 16);
}
static __device__ __forceinline__ float bf2f(unsigned short h) {
    return __uint_as_float(((unsigned int)h) << 16);
}

// async global->LDS, 16B per lane; LDS dest = wave-uniform base + lane*16
static __device__ __forceinline__ void load_lds16(const void* g, void* l) {
    __builtin_amdgcn_global_load_lds(
        (const __attribute__((address_space(1))) unsigned int*)g,
        (__attribute__((address_space(3))) unsigned int*)l, 16, 0, 0);
}

// ---------------------------------------------------------------- Phase A ---
// Fused: normalize codebook rows + pack B_ext image + zero ws header.
// One wave per code (4 codes/block, 256 blocks). chat = c / max(||c||,eps).
// Layout: chunk c (32 codes) = 48 KB of [nt(2)][ks24(24)][quad(4)][col(16)][j(8)]
// bf16: ks 0..7 = bf16hi(chat), 8..15 = bf16lo(chat), 16..23 = bf16hi(chat).
// Stage-1 uses only the (nt,ks 0..7) segments; redo uses all 48.
__global__ void vq_pack(const float* __restrict__ embed, unsigned short* __restrict__ bext,
                        int* __restrict__ wshdr) {
    __shared__ float cs[4][DIM];
    const int tid  = threadIdx.x;
    const int w    = tid >> 6;
    const int lane = tid & 63;
    const int k0   = blockIdx.x * 4;

    // block 0 zeroes the 20 KB ws header (counts, scalars, 1280 loss partials)
    if (blockIdx.x == 0) {
        for (int i = tid; i < 5120; i += 256) wshdr[i] = 0;
    }

    // wave w normalizes code k0+w into LDS
    {
        const int k = k0 + w;
        float4 v = *(const float4*)&embed[k * DIM + lane * 4];
        float s = v.x * v.x + v.y * v.y + v.z * v.z + v.w * v.w;
        #pragma unroll
        for (int off = 32; off; off >>= 1) s += __shfl_xor(s, off);
        float inv = 1.0f / fmaxf(sqrtf(s), 1e-12f);
        float4 nv;
        nv.x = v.x * inv; nv.y = v.y * inv; nv.z = v.z * inv; nv.w = v.w * inv;
        *(float4*)&cs[w][lane * 4] = nv;
    }
    __syncthreads();

    // emit 4 codes x 96 ushort8 groups = 384 16B stores
    for (int t = tid; t < 384; t += 256) {
        int lc  = t / 96;          // local code
        int g   = t - lc * 96;     // group
        int k   = k0 + lc;
        int kk0 = g * 8;
        int src, hi;
        if (kk0 < 256)      { src = kk0;       hi = 1; }
        else if (kk0 < 512) { src = kk0 - 256; hi = 0; }
        else                { src = kk0 - 512; hi = 1; }
        unsigned short r[8] __attribute__((aligned(16)));
        #pragma unroll
        for (int j = 0; j < 8; ++j) {
            float vv = cs[lc][src + j];
            unsigned short h = f2bf(vv);
            r[j] = hi ? h : f2bf(vv - bf2f(h));
        }
        int c = k >> 5, kin = k & 31;
        int nt = kin >> 4, col = kin & 15;
        int ks = kk0 >> 5, quad = (kk0 >> 3) & 3;
        size_t dst = (size_t)c * CHUNK_BYTES + (size_t)(((nt * 24 + ks) * 64) + quad * 16 + col) * 16;
        *(float4*)((char*)bext + dst) = *(const float4*)r;
    }
}

// ---------------------------------------------------------------- Phase B1 --
// Stage-1 screen: K=256 pure-bf16 MFMA argmax (zh . chat_hi only), 1/3 the
// MFMA/LDS work of the full-K kernel. Block: 128 tokens (4 waves x 2 m-tiles);
// 64 codes per staging iteration (2 x 16 KB sub-chunk images, 32 KB LDS,
// 4 blocks/CU). Top-2 tracked; gap >= MARGIN1 (>=10 sigma of the dropped
// hi-lo cross terms) -> final index, fused output (gather embed row, write
// z_q_st + idx float + counts + per-block loss partial). gap < MARGIN1 ->
// token appended to rlist1 for the full-K redo (no outputs written here).
__launch_bounds__(256, 4)
__global__ void vq_argmax1(const float* __restrict__ z,
                           const unsigned short* __restrict__ bext,
                           const float* __restrict__ embed,
                           int* __restrict__ fidx,
                           int* __restrict__ r1count, int* __restrict__ rlist1,
                           float* __restrict__ out, int* __restrict__ counts,
                           double* __restrict__ partials) {
    __shared__ unsigned short bbuf[16384];   // 32 KB = 2 x 16 KB sub-chunk images
    __shared__ double shl[4];

    const int tid  = threadIdx.x;
    const int w    = tid >> 6;
    const int lane = tid & 63;
    const int col  = lane & 15;
    const int quad = lane >> 4;
    const int tokBase = blockIdx.x * 128;

    // ---- A fragments (hi only): wave w owns tokens [w*32, w*32+32).
    // A[m=lane&15][k=quad*8+j] per m-tile, 8 k-steps of 32.
    bf16x8 ah[2][8];
    #pragma unroll
    for (int mt = 0; mt < 2; ++mt) {
        const float* zr = z + (size_t)(tokBase + w * 32 + mt * 16 + col) * DIM;
        #pragma unroll
        for (int ks = 0; ks < 8; ++ks) {
            float4 f0 = *(const float4*)(zr + ks * 32 + quad * 8);
            float4 f1 = *(const float4*)(zr + ks * 32 + quad * 8 + 4);
            float v[8] = {f0.x, f0.y, f0.z, f0.w, f1.x, f1.y, f1.z, f1.w};
            union { bf16x8 v; unsigned short u[8]; } th;
            #pragma unroll
            for (int j = 0; j < 8; ++j) th.u[j] = f2bf(v[j]);
            ah[mt][ks] = th.v;
        }
    }

    float best[2][4], second[2][4];
    int   bidx[2][4];
    #pragma unroll
    for (int mt = 0; mt < 2; ++mt)
        #pragma unroll
        for (int r = 0; r < 4; ++r) { best[mt][r] = -1e30f; second[mt][r] = -1e30f; bidx[mt][r] = 0; }

    for (int cc = 0; cc < 32; cc += 2) {
        __syncthreads();   // previous iteration's readers done
        {   // stage 2 sub-chunks (cc, cc+1): 32 local 1 KB segs, wave w takes 8.
            // local seg l in [0,16): nt = l>>3, ks = l&7 -> global seg nt*24+ks.
            #pragma unroll
            for (int i = 0; i < 8; ++i) {
                int lseg = w * 8 + i;
                int sub  = lseg >> 4;
                int l    = lseg & 15;
                int g    = l + ((l & 8) ? 16 : 0);   // nt*24 + ks
                load_lds16((const char*)bext + (size_t)(cc + sub) * CHUNK_BYTES
                                             + (size_t)g * 1024 + lane * 16,
                           (char*)bbuf + lseg * 1024);
            }
        }
        __syncthreads();   // drains vmcnt via barrier semantics

        #pragma unroll
        for (int sub = 0; sub < 2; ++sub) {
            f32x4 acc[2][2];
            #pragma unroll
            for (int mt = 0; mt < 2; ++mt)
                #pragma unroll
                for (int nt = 0; nt < 2; ++nt) acc[mt][nt] = (f32x4){0.f, 0.f, 0.f, 0.f};

            #pragma unroll
            for (int nt = 0; nt < 2; ++nt) {
                const unsigned short* bb = bbuf + sub * 8192 + nt * 4096;
                #pragma unroll
                for (int ks = 0; ks < 8; ++ks) {
                    bf16x8 b = *(const bf16x8*)&bb[ks * 512 + lane * 8];
                    acc[0][nt] = __builtin_amdgcn_mfma_f32_16x16x32_bf16(ah[0][ks], b, acc[0][nt], 0, 0, 0);
                    acc[1][nt] = __builtin_amdgcn_mfma_f32_16x16x32_bf16(ah[1][ks], b, acc[1][nt], 0, 0, 0);
                }
            }

            #pragma unroll
            for (int nt = 0; nt < 2; ++nt) {
                int code = (cc + sub) * 32 + nt * 16 + col;
                #pragma unroll
                for (int mt = 0; mt < 2; ++mt)
                    #pragma unroll
                    for (int r = 0; r < 4; ++r) {
                        float v = acc[mt][nt][r];
                        if (v > best[mt][r]) { second[mt][r] = best[mt][r]; best[mt][r] = v; bidx[mt][r] = code; }
                        else                 { second[mt][r] = fmaxf(second[mt][r], v); }
                    }
            }
        }
    }

    // Merge top-2 across the 16 D-columns. Post-butterfly B,S,I are uniform
    // across the wave's 16 cols -> flag decision is uniform too.
    #pragma unroll
    for (int mt = 0; mt < 2; ++mt)
        #pragma unroll
        for (int r = 0; r < 4; ++r) {
            float B = best[mt][r], S = second[mt][r];
            int   I = bidx[mt][r];
            #pragma unroll
            for (int off = 1; off < 16; off <<= 1) {
                float ob = __shfl_xor(B, off);
                float os = __shfl_xor(S, off);
                int   oi = __shfl_xor(I, off);
                if (ob > B) {
                    S = fmaxf(B, os);
                    B = ob; I = oi;
                } else {
                    if (ob == B && oi < I) I = oi;   // tie: first occurrence
                    S = fmaxf(S, ob);                // tie -> gap 0 -> redo
                }
            }
            int flag = (B - S < MARGIN1) ? 1 : 0;
            if (col == 0) {
                int token = tokBase + w * 32 + mt * 16 + quad * 4 + r;   // D row = quad*4+reg
                if (!flag) {
                    fidx[token] = I;
                    out[OUT_IDX + token] = (float)I;
                    atomicAdd(&counts[I], 1);
                } else {
                    int p = atomicAdd(r1count, 1);
                    rlist1[p] = token;
                }
            }
            bidx[mt][r] = I | (flag << 30);   // carry flag into gather loop
        }

    // ---- fused output for UNFLAGGED tokens (flagged handled by vq_redo).
    double lsum = 0.0;
    #pragma unroll
    for (int mt = 0; mt < 2; ++mt)
        #pragma unroll
        for (int r = 0; r < 4; ++r)
            #pragma unroll
            for (int q = 0; q < 4; ++q) {
                int enc = __shfl(bidx[mt][r], q * 16);   // wave-uniform
                if (enc & (1 << 30)) continue;           // flagged -> redo writes it
                int idxv  = enc;
                int token = tokBase + w * 32 + mt * 16 + q * 4 + r;
                float4 e  = *(const float4*)&embed[(size_t)idxv * DIM + lane * 4];
                float4 zz = *(const float4*)&z[(size_t)token * DIM + lane * 4];
                float4 rr, o;
                rr.x = e.x - zz.x; rr.y = e.y - zz.y; rr.z = e.z - zz.z; rr.w = e.w - zz.w;
                o.x = zz.x + rr.x; o.y = zz.y + rr.y; o.z = zz.z + rr.z; o.w = zz.w + rr.w;
                *(float4*)&out[(size_t)token * DIM + lane * 4] = o;
                lsum += (double)rr.x * rr.x + (double)rr.y * rr.y +
                        (double)rr.z * rr.z + (double)rr.w * rr.w;
            }

    #pragma unroll
    for (int off = 32; off; off >>= 1) lsum += __shfl_down(lsum, off);
    if (lane == 0) shl[w] = lsum;
    __syncthreads();
    if (tid == 0) partials[blockIdx.x] = shl[0] + shl[1] + shl[2] + shl[3];
}

// ---------------------------------------------------------------- Phase B2 --
// Full-K redo on the stage-1 near-ties (~5-10% of tokens): the proven K=768
// [zh,zh,zl].[ch,cl,ch] pipeline from round 4, over a compacted token list.
// Writes fidx / z_q_st / idx float / counts / loss partials for its tokens;
// gap < MARGIN2 -> fp64 recheck list.
__launch_bounds__(256, 2)
__global__ void vq_redo(const float* __restrict__ z,
                        const unsigned short* __restrict__ bext,
                        const float* __restrict__ embed,
                        const int* __restrict__ r1count, const int* __restrict__ rlist1,
                        int* __restrict__ fidx,
                        int* __restrict__ r2count, int* __restrict__ rlist2,
                        float* __restrict__ out, int* __restrict__ counts,
                        double* __restrict__ partials) {
    __shared__ unsigned short bbuf[CHUNK_BYTES / 2];   // 48 KB
    __shared__ double shl[4];

    const int tid  = threadIdx.x;
    const int w    = tid >> 6;
    const int lane = tid & 63;
    const int col  = lane & 15;
    const int quad = lane >> 4;
    const int cnt1 = *r1count;

    double lsum = 0.0;

    for (int base = blockIdx.x * 128; base < cnt1; base += gridDim.x * 128) {
        // ---- A fragments from scattered tokens (padded slots reuse last token)
        bf16x8 ah[2][8], al[2][8];
        #pragma unroll
        for (int mt = 0; mt < 2; ++mt) {
            int slot = base + w * 32 + mt * 16 + col;
            int tok  = rlist1[min(slot, cnt1 - 1)];
            const float* zr = z + (size_t)tok * DIM;
            #pragma unroll
            for (int ks = 0; ks < 8; ++ks) {
                float4 f0 = *(const float4*)(zr + ks * 32 + quad * 8);
                float4 f1 = *(const float4*)(zr + ks * 32 + quad * 8 + 4);
                float v[8] = {f0.x, f0.y, f0.z, f0.w, f1.x, f1.y, f1.z, f1.w};
                union { bf16x8 v; unsigned short u[8]; } th, tl;
                #pragma unroll
                for (int j = 0; j < 8; ++j) {
                    unsigned short h = f2bf(v[j]);
                    th.u[j] = h;
                    tl.u[j] = f2bf(v[j] - bf2f(h));
                }
                ah[mt][ks] = th.v;
                al[mt][ks] = tl.v;
            }
        }

        float best[2][4], second[2][4];
        int   bidx[2][4];
        #pragma unroll
        for (int mt = 0; mt < 2; ++mt)
            #pragma unroll
            for (int r = 0; r < 4; ++r) { best[mt][r] = -1e30f; second[mt][r] = -1e30f; bidx[mt][r] = 0; }

        for (int c = 0; c < 32; ++c) {
            __syncthreads();
            {   // stage 48 KB: wave w stages segments [w*12, w*12+12)
                const char* gsrc = (const char*)bext + (size_t)c * CHUNK_BYTES;
                #pragma unroll
                for (int i = 0; i < 12; ++i) {
                    int seg = w * 12 + i;
                    load_lds16(gsrc + (size_t)seg * 1024 + lane * 16,
                               (char*)bbuf + seg * 1024);
                }
            }
            __syncthreads();

            f32x4 acc[2][2];
            #pragma unroll
            for (int mt = 0; mt < 2; ++mt)
                #pragma unroll
                for (int nt = 0; nt < 2; ++nt) acc[mt][nt] = (f32x4){0.f, 0.f, 0.f, 0.f};

            #pragma unroll
            for (int nt = 0; nt < 2; ++nt) {
                const unsigned short* bb = bbuf + nt * 24 * 512;
                #pragma unroll
                for (int ks = 0; ks < 8; ++ks) {   // zh . ch
                    bf16x8 b = *(const bf16x8*)&bb[ks * 512 + lane * 8];
                    acc[0][nt] = __builtin_amdgcn_mfma_f32_16x16x32_bf16(ah[0][ks], b, acc[0][nt], 0, 0, 0);
                    acc[1][nt] = __builtin_amdgcn_mfma_f32_16x16x32_bf16(ah[1][ks], b, acc[1][nt], 0, 0, 0);
                }
                #pragma unroll
                for (int ks = 0; ks < 8; ++ks) {   // zh . cl
                    bf16x8 b = *(const bf16x8*)&bb[(8 + ks) * 512 + lane * 8];
                    acc[0][nt] = __builtin_amdgcn_mfma_f32_16x16x32_bf16(ah[0][ks], b, acc[0][nt], 0, 0, 0);
                    acc[1][nt] = __builtin_amdgcn_mfma_f32_16x16x32_bf16(ah[1][ks], b, acc[1][nt], 0, 0, 0);
                }
                #pragma unroll
                for (int ks = 0; ks < 8; ++ks) {   // zl . ch
                    bf16x8 b = *(const bf16x8*)&bb[(16 + ks) * 512 + lane * 8];
                    acc[0][nt] = __builtin_amdgcn_mfma_f32_16x16x32_bf16(al[0][ks], b, acc[0][nt], 0, 0, 0);
                    acc[1][nt] = __builtin_amdgcn_mfma_f32_16x16x32_bf16(al[1][ks], b, acc[1][nt], 0, 0, 0);
                }
            }

            #pragma unroll
            for (int nt = 0; nt < 2; ++nt) {
                int code = c * 32 + nt * 16 + col;
                #pragma unroll
                for (int mt = 0; mt < 2; ++mt)
                    #pragma unroll
                    for (int r = 0; r < 4; ++r) {
                        float v = acc[mt][nt][r];
                        if (v > best[mt][r]) { second[mt][r] = best[mt][r]; best[mt][r] = v; bidx[mt][r] = code; }
                        else                 { second[mt][r] = fmaxf(second[mt][r], v); }
                    }
            }
        }

        // merge + write (guarded by slot < cnt1)
        #pragma unroll
        for (int mt = 0; mt < 2; ++mt)
            #pragma unroll
            for (int r = 0; r < 4; ++r) {
                float B = best[mt][r], S = second[mt][r];
                int   I = bidx[mt][r];
                #pragma unroll
                for (int off = 1; off < 16; off <<= 1) {
                    float ob = __shfl_xor(B, off);
                    float os = __shfl_xor(S, off);
                    int   oi = __shfl_xor(I, off);
                    if (ob > B) {
                        S = fmaxf(B, os);
                        B = ob; I = oi;
                    } else {
                        if (ob == B && oi < I) I = oi;
                        S = fmaxf(S, ob);
                    }
                }
                bidx[mt][r] = I;
                if (col == 0) {
                    int slot = base + w * 32 + mt * 16 + quad * 4 + r;
                    if (slot < cnt1) {
                        int token = rlist1[slot];
                        fidx[token] = I;
                        out[OUT_IDX + token] = (float)I;
                        atomicAdd(&counts[I], 1);
                        if (B - S < MARGIN2) {
                            int p = atomicAdd(r2count, 1);
                            rlist2[p] = token;
                        }
                    }
                }
            }

        // fused output for this iteration's valid tokens
        #pragma unroll
        for (int mt = 0; mt < 2; ++mt)
            #pragma unroll
            for (int r = 0; r < 4; ++r)
                #pragma unroll
                for (int q = 0; q < 4; ++q) {
                    int slot = base + w * 32 + mt * 16 + q * 4 + r;
                    if (slot >= cnt1) continue;         // wave-uniform
                    int idxv  = __shfl(bidx[mt][r], q * 16);
                    int token = rlist1[slot];
                    float4 e  = *(const float4*)&embed[(size_t)idxv * DIM + lane * 4];
                    float4 zz = *(const float4*)&z[(size_t)token * DIM + lane * 4];
                    float4 rr, o;
                    rr.x = e.x - zz.x; rr.y = e.y - zz.y; rr.z = e.z - zz.z; rr.w = e.w - zz.w;
                    o.x = zz.x + rr.x; o.y = zz.y + rr.y; o.z = zz.z + rr.z; o.w = zz.w + rr.w;
                    *(float4*)&out[(size_t)token * DIM + lane * 4] = o;
                    lsum += (double)rr.x * rr.x + (double)rr.y * rr.y +
                            (double)rr.z * rr.z + (double)rr.w * rr.w;
                }
    }

    // block loss partial (accumulated across grid-stride iterations)
    #pragma unroll
    for (int off = 32; off; off >>= 1) lsum += __shfl_down(lsum, off);
    if (lane == 0) shl[w] = lsum;
    __syncthreads();
    if (tid == 0) partials[1024 + blockIdx.x] = shl[0] + shl[1] + shl[2] + shl[3];
}

// ---------------------------------------------------------------- Phase R ---
// Exact fp64 argmax for flagged tokens + fixup of out/counts/loss.
__global__ void vq_recheck(const float* __restrict__ z, const float* __restrict__ embed,
                           const int* __restrict__ r2count, const int* __restrict__ rlist2,
                           int* __restrict__ fidx, float* __restrict__ out,
                           int* __restrict__ counts, double* __restrict__ lossFix) {
    __shared__ double zd[DIM];
    __shared__ double rv[256];
    __shared__ int    rix[256];
    __shared__ int    s_old, s_new;
    const int cnt = *r2count;
    for (int li = blockIdx.x; li < cnt; li += gridDim.x) {
        int token = rlist2[li];
        __syncthreads();
        zd[threadIdx.x] = (double)z[(size_t)token * DIM + threadIdx.x];
        if (threadIdx.x == 0) s_old = fidx[token];
        __syncthreads();
        double bv = -1e300;
        int    bi = 0;
        #pragma unroll
        for (int j = 0; j < 4; ++j) {
            int k = threadIdx.x * 4 + j;   // ascending per thread
            const float* e = &embed[k * DIM];
            double acc = 0.0, nrm = 0.0;
            for (int d = 0; d < DIM; d += 4) {
                float4 ef = *(const float4*)&e[d];
                acc += (double)ef.x * zd[d]     + (double)ef.y * zd[d + 1] +
                       (double)ef.z * zd[d + 2] + (double)ef.w * zd[d + 3];
                nrm += (double)ef.x * ef.x + (double)ef.y * ef.y +
                       (double)ef.z * ef.z + (double)ef.w * ef.w;
            }
            double val = acc / fmax(sqrt(nrm), 1e-12);   // 1/||z|| scale dropped
            if (val > bv) { bv = val; bi = k; }
        }
        rv[threadIdx.x]  = bv;
        rix[threadIdx.x] = bi;
        __syncthreads();
        for (int s = 128; s; s >>= 1) {
            if (threadIdx.x < s) {
                double v2 = rv[threadIdx.x + s];
                int    i2 = rix[threadIdx.x + s];
                if (v2 > rv[threadIdx.x] ||
                    (v2 == rv[threadIdx.x] && i2 < rix[threadIdx.x])) {
                    rv[threadIdx.x] = v2;
                    rix[threadIdx.x] = i2;
                }
            }
            __syncthreads();
        }
        if (threadIdx.x == 0) {
            s_new = rix[0];
            if (s_new != s_old) {
                fidx[token] = s_new;
                out[OUT_IDX + token] = (float)s_new;
                atomicAdd(&counts[s_old], -1);
                atomicAdd(&counts[s_new], 1);
            }
        }
        __syncthreads();
        if (s_new != s_old && threadIdx.x < 64) {
            int lane = threadIdx.x;
            float4 en = *(const float4*)&embed[(size_t)s_new * DIM + lane * 4];
            float4 eo = *(const float4*)&embed[(size_t)s_old * DIM + lane * 4];
            float4 zz = *(const float4*)&z[(size_t)token * DIM + lane * 4];
            float4 rn, ro, o;
            rn.x = en.x - zz.x; rn.y = en.y - zz.y; rn.z = en.z - zz.z; rn.w = en.w - zz.w;
            ro.x = eo.x - zz.x; ro.y = eo.y - zz.y; ro.z = eo.z - zz.z; ro.w = eo.w - zz.w;
            o.x = zz.x + rn.x; o.y = zz.y + rn.y; o.z = zz.z + rn.z; o.w = zz.w + rn.w;
            *(float4*)&out[(size_t)token * DIM + lane * 4] = o;
            double d = (double)rn.x * rn.x + (double)rn.y * rn.y +
                       (double)rn.z * rn.z + (double)rn.w * rn.w -
                       ((double)ro.x * ro.x + (double)ro.y * ro.y +
                        (double)ro.z * ro.z + (double)ro.w * ro.w);
            #pragma unroll
            for (int off = 32; off; off >>= 1) d += __shfl_down(d, off);
            if (lane == 0) atomicAdd(lossFix, d);
        }
    }
}

// ---------------------------------------------------------------- Phase D ---
// 1 block: sum 1280 loss partials + lossFix -> loss; counts entropy -> perp.
__global__ void vq_finalize(const int* __restrict__ counts,
                            const double* __restrict__ partials,
                            const double* __restrict__ lossFix,
                            float* __restrict__ out) {
    __shared__ double sh[256];
    __shared__ double sl[256];
    double s = 0.0, ls = 0.0;
    for (int b = threadIdx.x; b < K_CODE; b += 256) {
        double p = (double)counts[b] / (double)N_TOK;
        s += p * log(p + 1e-10);   // p==0 contributes exactly 0
    }
    for (int b = threadIdx.x; b < 1280; b += 256) ls += partials[b];
    sh[threadIdx.x] = s;
    sl[threadIdx.x] = ls;
    __syncthreads();
    for (int st = 128; st; st >>= 1) {
        if (threadIdx.x < st) {
            sh[threadIdx.x] += sh[threadIdx.x + st];
            sl[threadIdx.x] += sl[threadIdx.x + st];
        }
        __syncthreads();
    }
    if (threadIdx.x == 0) {
        out[OUT_PERP] = (float)exp(-sh[0]);
        out[OUT_LOSS] = (float)(1.25 * (sl[0] + *lossFix) / (double)(N_TOK) / (double)(DIM));
    }
}

// ----------------------------------------------------------------- launch ---
extern "C" void kernel_launch(void* const* d_in, const int* in_sizes, int n_in,
                              void* d_out, int out_size, void* d_ws, size_t ws_size,
                              hipStream_t stream) {
    const float* z     = (const float*)d_in[0];
    const float* embed = (const float*)d_in[1];
    float* out = (float*)d_out;
    char*  ws  = (char*)d_ws;

    int*            counts  = (int*)   (ws + WS_COUNTS);
    double*         lossFix = (double*)(ws + WS_LOSSFIX);
    int*            r2count = (int*)   (ws + WS_RCOUNT2);
    int*            r1count = (int*)   (ws + WS_RCOUNT1);
    double*         parts   = (double*)(ws + WS_PART);
    int*            fidx    = (int*)   (ws + WS_FIDX);
    int*            rlist2  = (int*)   (ws + WS_RLIST2);
    int*            rlist1  = (int*)   (ws + WS_RLIST1);
    unsigned short* bext    = (unsigned short*)(ws + WS_BEXT);

    vq_pack    <<<256,  256, 0, stream>>>(embed, bext, (int*)ws);
    vq_argmax1 <<<N_TOK / 128, 256, 0, stream>>>(z, bext, embed, fidx, r1count, rlist1,
                                                 out, counts, parts);
    vq_redo    <<<256,  256, 0, stream>>>(z, bext, embed, r1count, rlist1, fidx,
                                          r2count, rlist2, out, counts, parts);
    vq_recheck <<<512,  256, 0, stream>>>(z, embed, r2count, rlist2, fidx, out, counts, lossFix);
    vq_finalize<<<1,    256, 0, stream>>>(counts, parts, lossFix, out);
}